// Round 3
// baseline (288.700 us; speedup 1.0000x reference)
//
#include <hip/hip_runtime.h>

#define N_NODES 50000
#define N_EDGES 800000
#define IN_F    128
#define HEADS   8
#define OUT_F   16

typedef unsigned short u16;
typedef __attribute__((ext_vector_type(8))) short bf16x8;   // 4 VGPRs
typedef __attribute__((ext_vector_type(4))) float f32x4;

__device__ __forceinline__ float bf2f(u16 u) {
    return __uint_as_float(((unsigned)u) << 16);
}
__device__ __forceinline__ u16 f2bf(float f) {
    unsigned u = __float_as_uint(f);
    unsigned r = 0x7fffu + ((u >> 16) & 1u);
    return (u16)((u + r) >> 16);
}
// dtype-adaptive float load: bf=true -> buffer is bf16, else fp32
__device__ __forceinline__ float ldf(const void* p, int i, bool bf) {
    return bf ? bf2f(((const u16*)p)[i]) : ((const float*)p)[i];
}

// ------------------------------------------------------------- dtype probe
__global__ void probe_dtype(const void* __restrict__ h, int* __restrict__ flag) {
    if (threadIdx.x == 0 && blockIdx.x == 0) {
        const u16* u = (const u16*)h;
        int cnt = 0;
        for (int i = 0; i < 128; ++i) {
            int e = (u[i] >> 7) & 0xFF;
            if (e >= 90 && e <= 141) cnt++;
        }
        *flag = (cnt >= 110) ? 1 : 0;
    }
}

// ---------------------------------------------------------------- zero deg
__global__ __launch_bounds__(256) void zero_deg(int* __restrict__ deg) {
    int i = blockIdx.x * 256 + threadIdx.x;
    if (i < N_NODES) deg[i] = 0;
}

// ------------------------------------------------- node projection (MFMA)
// ht2[n, f*8 + h] = head-interleaved projection (f=feat 0..15, h=head 0..7):
// the fused pass reads one bf16x8 (16B) per lane = 8 head-values of one
// feature; 16 lanes cover the whole 256B row coalesced.
#define WT_STRIDE 136   // bf16 units; 272 B per row: 16B-aligned, banks spread
__global__ __launch_bounds__(256) void node_proj_mfma(
    const void* __restrict__ h, const void* __restrict__ Wn,
    const void* __restrict__ a_srcp, const void* __restrict__ a_dstp,
    const int* __restrict__ flag,
    u16* __restrict__ ht, float* __restrict__ s_src, float* __restrict__ s_dst)
{
    const bool bf = (*flag) != 0;
    __shared__ u16 Wsh[IN_F * WT_STRIDE];   // 34.8 KB, Wt[c][k]
    const int tid = threadIdx.x;

    // stage W transposed (coalesced read, scattered LDS write)
    for (int i = tid; i < IN_F * IN_F; i += 256) {
        int k = i >> 7, c = i & 127;
        u16 v = bf ? ((const u16*)Wn)[i] : f2bf(((const float*)Wn)[i]);
        Wsh[c * WT_STRIDE + k] = v;
    }
    __syncthreads();

    const int wave = tid >> 6, lane = tid & 63;
    const int m = lane & 15, q = lane >> 4;
    const int row_t = blockIdx.x * 64 + wave * 16;   // this wave's 16-row tile

    // A fragments for K=128 (4 chunks of 32)
    bf16x8 afr[4];
    int arow = row_t + m;
    if (arow >= N_NODES) arow = N_NODES - 1;         // clamp; writes guarded
    if (bf) {
        const u16* hp = (const u16*)h + (size_t)arow * IN_F;
        #pragma unroll
        for (int kt = 0; kt < 4; ++kt)
            afr[kt] = *(const bf16x8*)(hp + kt * 32 + q * 8);
    } else {
        const float* hp = (const float*)h + (size_t)arow * IN_F;
        #pragma unroll
        for (int kt = 0; kt < 4; ++kt) {
            bf16x8 t;
            #pragma unroll
            for (int j = 0; j < 8; ++j) t[j] = (short)f2bf(hp[kt * 32 + q * 8 + j]);
            afr[kt] = t;
        }
    }

    f32x4 accs[8];                                    // all 8 head tiles live
    #pragma unroll
    for (int ct = 0; ct < 8; ++ct) {                  // col tile == head
        f32x4 acc = {0.f, 0.f, 0.f, 0.f};
        #pragma unroll
        for (int kt = 0; kt < 4; ++kt) {
            bf16x8 bfr = *(const bf16x8*)(Wsh + (ct * 16 + m) * WT_STRIDE + kt * 32 + q * 8);
            acc = __builtin_amdgcn_mfma_f32_16x16x32_bf16(afr[kt], bfr, acc, 0, 0, 0);
        }
        accs[ct] = acc;
        const float asv = ldf(a_srcp, ct * 16 + m, bf);
        const float adv = ldf(a_dstp, ct * 16 + m, bf);
        float v1[4], v2[4];
        #pragma unroll
        for (int r = 0; r < 4; ++r) {
            v1[r] = acc[r] * asv;
            v2[r] = acc[r] * adv;
        }
        #pragma unroll
        for (int o = 1; o < 16; o <<= 1) {
            #pragma unroll
            for (int r = 0; r < 4; ++r) {
                v1[r] += __shfl_xor(v1[r], o, 16);
                v2[r] += __shfl_xor(v2[r], o, 16);
            }
        }
        if (m == 0) {
            #pragma unroll
            for (int r = 0; r < 4; ++r) {
                int grow = row_t + q * 4 + r;
                if (grow < N_NODES) {
                    s_src[grow * HEADS + ct] = v1[r];
                    s_dst[grow * HEADS + ct] = v2[r];
                }
            }
        }
    }

    // packed head-interleaved store: lane(m,q) owns ht2[row][m*8 + 0..7]
    #pragma unroll
    for (int r = 0; r < 4; ++r) {
        int grow = row_t + q * 4 + r;
        if (grow < N_NODES) {
            bf16x8 o;
            #pragma unroll
            for (int ct = 0; ct < 8; ++ct) o[ct] = (short)f2bf(accs[ct][r]);
            *(bf16x8*)(ht + (size_t)grow * IN_F + m * 8) = o;
        }
    }
}

// ---------------------------------------------------------------- histogram
__global__ __launch_bounds__(256) void edge_histogram(const int* __restrict__ ei,
                                                      int* __restrict__ deg) {
    int e = blockIdx.x * 256 + threadIdx.x;
    if (e < N_EDGES) atomicAdd(&deg[ei[N_EDGES + e]], 1);
}

// -------------------------------------------------------- exclusive scan
// Single block of 1024 threads, 49 chunk iterations over 50000 degrees.
__global__ __launch_bounds__(1024) void scan_deg(const int* __restrict__ deg,
                                                 int* __restrict__ csr,
                                                 int* __restrict__ cursor) {
    __shared__ int wsums[16];
    const int tid = threadIdx.x, lane = tid & 63, wid = tid >> 6;
    int running = 0;
    for (int base = 0; base < N_NODES; base += 1024) {
        int i = base + tid;
        int v = (i < N_NODES) ? deg[i] : 0;
        int x = v;
        #pragma unroll
        for (int o = 1; o < 64; o <<= 1) {
            int y = __shfl_up(x, o, 64);
            if (lane >= o) x += y;
        }
        if (lane == 63) wsums[wid] = x;
        __syncthreads();
        if (wid == 0) {
            int s = (lane < 16) ? wsums[lane] : 0;
            #pragma unroll
            for (int o = 1; o < 16; o <<= 1) {
                int y = __shfl_up(s, o, 16);
                if ((lane & 15) >= o) s += y;
            }
            if (lane < 16) wsums[lane] = s;
        }
        __syncthreads();
        int woff = (wid > 0) ? wsums[wid - 1] : 0;
        int excl = running + woff + (x - v);
        if (i < N_NODES) { csr[i] = excl; cursor[i] = excl; }
        running += wsums[15];
        __syncthreads();   // protect wsums for next chunk
    }
    if (tid == 0) csr[N_NODES] = running;
}

// ------------------------------------------------------------- scatter
// Per edge: compute the 8 exp(leaky(attn)) scores (src/dst scores are ready),
// claim a slot in dst's CSR bucket, write src id + 8 scores.
// No max-shift: attn is statistically bounded (|a| < ~15 << 88), exp() safe.
__global__ __launch_bounds__(256) void scatter_edges(
    const int* __restrict__ ei, const void* __restrict__ ef,
    const void* __restrict__ We, const int* __restrict__ flag,
    const float* __restrict__ s_src, const float* __restrict__ s_dst,
    int* __restrict__ cursor, int* __restrict__ srcs, float* __restrict__ ex8)
{
    const bool bf = (*flag) != 0;
    int e = blockIdx.x * 256 + threadIdx.x;
    if (e >= N_EDGES) return;
    int src = ei[e];
    int dst = ei[N_EDGES + e];
    float efv = ldf(ef, e, bf);
    const float4* sp = (const float4*)(s_src + src * HEADS);
    const float4* dp = (const float4*)(s_dst + dst * HEADS);
    float4 sa = sp[0], sb = sp[1];
    float4 da = dp[0], db = dp[1];
    float a8[8] = {sa.x + da.x, sa.y + da.y, sa.z + da.z, sa.w + da.w,
                   sb.x + db.x, sb.y + db.y, sb.z + db.z, sb.w + db.w};
    int pos = atomicAdd(&cursor[dst], 1);
    srcs[pos] = src;
    float ex[8];
    #pragma unroll
    for (int hh = 0; hh < 8; ++hh) {
        float a = a8[hh] + efv * ldf(We, hh, bf);
        a = (a > 0.0f) ? a : 0.2f * a;   // leaky_relu 0.2
        ex[hh] = __expf(a);
    }
    float4 x0 = {ex[0], ex[1], ex[2], ex[3]};
    float4 x1 = {ex[4], ex[5], ex[6], ex[7]};
    float4* xp = (float4*)(ex8 + (size_t)pos * 8);
    xp[0] = x0;
    xp[1] = x1;
}

// --------------------------------------------------- fused aggregation
// One 16-lane group per dst node walks its CSR bucket: accumulates per-head
// numerators (lane = feature, 8 regs) AND the per-head exp-sum in registers,
// then normalizes, head-means, and writes the FINAL output. No atomics, no
// sum_exp buffer, no finalize pass. ht gather hand-pipelined 1 deep.
__global__ __launch_bounds__(256) void fused_aggregate(
    const int* __restrict__ csr, const int* __restrict__ srcs,
    const float* __restrict__ ex8, const u16* __restrict__ ht,
    const int* __restrict__ flag, void* __restrict__ out)
{
    const bool bf = (*flag) != 0;
    int g = blockIdx.x * 16 + (threadIdx.x >> 4);
    if (g >= N_NODES) return;
    int lane = threadIdx.x & 15;
    int beg = csr[g], end = csr[g + 1];

    float num[8] = {0.f, 0.f, 0.f, 0.f, 0.f, 0.f, 0.f, 0.f};
    float ssum = 0.f;

    int i = beg;
    float exN = 0.f;
    bf16x8 vN = {0, 0, 0, 0, 0, 0, 0, 0};
    if (i < end) {
        int s0 = srcs[i];
        exN = ex8[(size_t)i * 8 + (lane & 7)];
        vN = *(const bf16x8*)(ht + (size_t)s0 * IN_F + lane * 8);
    }
    for (; i < end; ++i) {
        float exC = exN;
        bf16x8 vC = vN;
        int j = i + 1;
        if (j < end) {                       // prefetch next edge
            int s1 = srcs[j];
            exN = ex8[(size_t)j * 8 + (lane & 7)];
            vN = *(const bf16x8*)(ht + (size_t)s1 * IN_F + lane * 8);
        }
        ssum += exC;                         // head (lane&7), duplicated halves
        #pragma unroll
        for (int hh = 0; hh < 8; ++hh) {
            float ah = __shfl(exC, hh, 16);
            num[hh] = fmaf(ah, bf2f((u16)vC[hh]), num[hh]);
        }
    }

    float o = 0.f;
    #pragma unroll
    for (int hh = 0; hh < 8; ++hh) {
        float sh = __shfl(ssum, hh, 16);
        o += num[hh] / fmaxf(sh, 1e-12f);
    }
    o *= 0.125f;                              // head mean
    if (bf) ((u16*)out)[(size_t)g * OUT_F + lane] = f2bf(o);
    else    ((float*)out)[(size_t)g * OUT_F + lane] = o;
}

// ---------------------------------------------------------------- launch
extern "C" void kernel_launch(void* const* d_in, const int* in_sizes, int n_in,
                              void* d_out, int out_size, void* d_ws, size_t ws_size,
                              hipStream_t stream) {
    const void* h     = d_in[0];
    const int*  ei    = (const int*)d_in[1];
    const void* efeat = d_in[2];
    const void* Wn    = d_in[3];
    const void* We    = d_in[4];
    const void* a_src = d_in[5];
    const void* a_dst = d_in[6];

    char* ws = (char*)d_ws;
    int*   flag    = (int*)ws;   ws += 256;
    u16*   ht      = (u16*)ws;   ws += (size_t)N_NODES * IN_F * 2;     // 12.8 MB
    float* s_src   = (float*)ws; ws += (size_t)N_NODES * HEADS * 4;    // 1.6 MB
    float* s_dst   = (float*)ws; ws += (size_t)N_NODES * HEADS * 4;    // 1.6 MB
    int*   deg     = (int*)ws;   ws += (size_t)50048 * 4;              // padded
    int*   csr     = (int*)ws;   ws += (size_t)50048 * 4;              // N+1 used
    int*   cursor  = (int*)ws;   ws += (size_t)50048 * 4;
    int*   srcs    = (int*)ws;   ws += (size_t)N_EDGES * 4;            // 3.2 MB
    float* ex8     = (float*)ws; ws += (size_t)N_EDGES * HEADS * 4;    // 25.6 MB

    hipLaunchKernelGGL(probe_dtype, dim3(1), dim3(64), 0, stream, h, flag);
    hipLaunchKernelGGL(zero_deg, dim3((N_NODES + 255) / 256), dim3(256),
                       0, stream, deg);
    hipLaunchKernelGGL(node_proj_mfma, dim3((N_NODES + 63) / 64), dim3(256),
                       0, stream, h, Wn, a_src, a_dst, flag, ht, s_src, s_dst);
    hipLaunchKernelGGL(edge_histogram, dim3((N_EDGES + 255) / 256), dim3(256),
                       0, stream, ei, deg);
    hipLaunchKernelGGL(scan_deg, dim3(1), dim3(1024), 0, stream, deg, csr, cursor);
    hipLaunchKernelGGL(scatter_edges, dim3((N_EDGES + 255) / 256), dim3(256),
                       0, stream, ei, efeat, We, flag, s_src, s_dst,
                       cursor, srcs, ex8);
    hipLaunchKernelGGL(fused_aggregate, dim3((N_NODES + 15) / 16), dim3(256),
                       0, stream, csr, srcs, ex8, ht, flag, d_out);
}

// Round 4
// 279.641 us; speedup vs baseline: 1.0324x; 1.0324x over previous
//
#include <hip/hip_runtime.h>

#define N_NODES 50000
#define N_EDGES 800000
#define IN_F    128
#define HEADS   8
#define OUT_F   16

typedef unsigned short u16;
typedef __attribute__((ext_vector_type(8))) short bf16x8;   // 4 VGPRs
typedef __attribute__((ext_vector_type(4))) float f32x4;

__device__ __forceinline__ float bf2f(u16 u) {
    return __uint_as_float(((unsigned)u) << 16);
}
__device__ __forceinline__ u16 f2bf(float f) {
    unsigned u = __float_as_uint(f);
    unsigned r = 0x7fffu + ((u >> 16) & 1u);
    return (u16)((u + r) >> 16);
}
// dtype-adaptive float load: bf=true -> buffer is bf16, else fp32
__device__ __forceinline__ float ldf(const void* p, int i, bool bf) {
    return bf ? bf2f(((const u16*)p)[i]) : ((const float*)p)[i];
}

// ------------------------------------------------------------- dtype probe
__global__ void probe_dtype(const void* __restrict__ h, int* __restrict__ flag) {
    if (threadIdx.x == 0 && blockIdx.x == 0) {
        const u16* u = (const u16*)h;
        int cnt = 0;
        for (int i = 0; i < 128; ++i) {
            int e = (u[i] >> 7) & 0xFF;
            if (e >= 90 && e <= 141) cnt++;
        }
        *flag = (cnt >= 110) ? 1 : 0;
    }
}

// ------------------------------------------------- node projection (MFMA)
// ht2[n, f*8 + h] = head-interleaved projection (f=feat 0..15, h=head 0..7):
// the fused pass reads one bf16x8 (16B) per lane = 8 head-values of one
// feature; 16 lanes cover the whole 256B row coalesced.
#define WT_STRIDE 136   // bf16 units; 272 B per row: 16B-aligned, banks spread
__global__ __launch_bounds__(256) void node_proj_mfma(
    const void* __restrict__ h, const void* __restrict__ Wn,
    const void* __restrict__ a_srcp, const void* __restrict__ a_dstp,
    const int* __restrict__ flag,
    u16* __restrict__ ht, float* __restrict__ s_src, float* __restrict__ s_dst)
{
    const bool bf = (*flag) != 0;
    __shared__ u16 Wsh[IN_F * WT_STRIDE];   // 34.8 KB, Wt[c][k]
    const int tid = threadIdx.x;

    // stage W transposed (coalesced read, scattered LDS write)
    for (int i = tid; i < IN_F * IN_F; i += 256) {
        int k = i >> 7, c = i & 127;
        u16 v = bf ? ((const u16*)Wn)[i] : f2bf(((const float*)Wn)[i]);
        Wsh[c * WT_STRIDE + k] = v;
    }
    __syncthreads();

    const int wave = tid >> 6, lane = tid & 63;
    const int m = lane & 15, q = lane >> 4;
    const int row_t = blockIdx.x * 64 + wave * 16;   // this wave's 16-row tile

    // A fragments for K=128 (4 chunks of 32)
    bf16x8 afr[4];
    int arow = row_t + m;
    if (arow >= N_NODES) arow = N_NODES - 1;         // clamp; writes guarded
    if (bf) {
        const u16* hp = (const u16*)h + (size_t)arow * IN_F;
        #pragma unroll
        for (int kt = 0; kt < 4; ++kt)
            afr[kt] = *(const bf16x8*)(hp + kt * 32 + q * 8);
    } else {
        const float* hp = (const float*)h + (size_t)arow * IN_F;
        #pragma unroll
        for (int kt = 0; kt < 4; ++kt) {
            bf16x8 t;
            #pragma unroll
            for (int j = 0; j < 8; ++j) t[j] = (short)f2bf(hp[kt * 32 + q * 8 + j]);
            afr[kt] = t;
        }
    }

    f32x4 accs[8];                                    // all 8 head tiles live
    #pragma unroll
    for (int ct = 0; ct < 8; ++ct) {                  // col tile == head
        f32x4 acc = {0.f, 0.f, 0.f, 0.f};
        #pragma unroll
        for (int kt = 0; kt < 4; ++kt) {
            bf16x8 bfr = *(const bf16x8*)(Wsh + (ct * 16 + m) * WT_STRIDE + kt * 32 + q * 8);
            acc = __builtin_amdgcn_mfma_f32_16x16x32_bf16(afr[kt], bfr, acc, 0, 0, 0);
        }
        accs[ct] = acc;
        const float asv = ldf(a_srcp, ct * 16 + m, bf);
        const float adv = ldf(a_dstp, ct * 16 + m, bf);
        float v1[4], v2[4];
        #pragma unroll
        for (int r = 0; r < 4; ++r) {
            v1[r] = acc[r] * asv;
            v2[r] = acc[r] * adv;
        }
        #pragma unroll
        for (int o = 1; o < 16; o <<= 1) {
            #pragma unroll
            for (int r = 0; r < 4; ++r) {
                v1[r] += __shfl_xor(v1[r], o, 16);
                v2[r] += __shfl_xor(v2[r], o, 16);
            }
        }
        if (m == 0) {
            #pragma unroll
            for (int r = 0; r < 4; ++r) {
                int grow = row_t + q * 4 + r;
                if (grow < N_NODES) {
                    s_src[grow * HEADS + ct] = v1[r];
                    s_dst[grow * HEADS + ct] = v2[r];
                }
            }
        }
    }

    // packed head-interleaved store: lane(m,q) owns ht2[row][m*8 + 0..7]
    #pragma unroll
    for (int r = 0; r < 4; ++r) {
        int grow = row_t + q * 4 + r;
        if (grow < N_NODES) {
            bf16x8 o;
            #pragma unroll
            for (int ct = 0; ct < 8; ++ct) o[ct] = (short)f2bf(accs[ct][r]);
            *(bf16x8*)(ht + (size_t)grow * IN_F + m * 8) = o;
        }
    }
}

// ---------------------------------------------------------------- histogram
__global__ __launch_bounds__(256) void edge_histogram(const int* __restrict__ ei,
                                                      int* __restrict__ deg) {
    int e = blockIdx.x * 256 + threadIdx.x;
    if (e < N_EDGES) atomicAdd(&deg[ei[N_EDGES + e]], 1);
}

// -------------------------------------------------------- exclusive scan
// Single block, 1024 threads x int4 each = 4096 elems/chunk, 13 chunks.
__global__ __launch_bounds__(1024) void scan_deg(const int* __restrict__ deg,
                                                 int* __restrict__ csr,
                                                 int* __restrict__ cursor) {
    __shared__ int wsums[16];
    __shared__ int carry_sh;
    const int tid = threadIdx.x, lane = tid & 63, wid = tid >> 6;
    if (tid == 0) carry_sh = 0;
    __syncthreads();
    for (int base = 0; base < N_NODES; base += 4096) {
        int idx = base + tid * 4;
        int4 v = {0, 0, 0, 0};
        if (idx + 3 < N_NODES) {
            v = *(const int4*)(deg + idx);
        } else if (idx < N_NODES) {
            v.x = deg[idx];
            if (idx + 1 < N_NODES) v.y = deg[idx + 1];
            if (idx + 2 < N_NODES) v.z = deg[idx + 2];
        }
        int t1 = v.x + v.y, t2 = t1 + v.z, t3 = t2 + v.w;
        int x = t3;                                   // wave inclusive scan
        #pragma unroll
        for (int o = 1; o < 64; o <<= 1) {
            int y = __shfl_up(x, o, 64);
            if (lane >= o) x += y;
        }
        if (lane == 63) wsums[wid] = x;
        __syncthreads();
        if (wid == 0) {
            int s = (lane < 16) ? wsums[lane] : 0;
            #pragma unroll
            for (int o = 1; o < 16; o <<= 1) {
                int y = __shfl_up(s, o, 16);
                if ((lane & 15) >= o) s += y;
            }
            if (lane < 16) wsums[lane] = s;
        }
        __syncthreads();
        int c = carry_sh;
        int woff = (wid > 0) ? wsums[wid - 1] : 0;
        int total = wsums[15];
        int excl = c + woff + (x - t3);
        int4 o4 = {excl, excl + v.x, excl + t1, excl + t2};
        if (idx + 3 < N_NODES) {
            *(int4*)(csr + idx) = o4;
            *(int4*)(cursor + idx) = o4;
        } else if (idx < N_NODES) {
            csr[idx] = o4.x; cursor[idx] = o4.x;
            if (idx + 1 < N_NODES) { csr[idx + 1] = o4.y; cursor[idx + 1] = o4.y; }
            if (idx + 2 < N_NODES) { csr[idx + 2] = o4.z; cursor[idx + 2] = o4.z; }
        }
        __syncthreads();                              // all read c before update
        if (tid == 0) carry_sh = c + total;
        __syncthreads();
    }
    if (tid == 0) csr[N_NODES] = carry_sh;
}

// ------------------------------------------------------------- scatter
// Minimal 8B payload: (src, edge_id). Scores computed by the consumer.
__global__ __launch_bounds__(256) void scatter_edges(
    const int* __restrict__ ei, int* __restrict__ cursor,
    int2* __restrict__ edges)
{
    int e = blockIdx.x * 256 + threadIdx.x;
    if (e >= N_EDGES) return;
    int src = ei[e];
    int dst = ei[N_EDGES + e];
    int pos = atomicAdd(&cursor[dst], 1);
    edges[pos] = make_int2(src, e);
}

// --------------------------------------------------- fused aggregation
// One 16-lane group per dst node walks its CSR bucket: computes attn+exp
// inline (s_dst/We are lane-local; edges[i] and ef[eid] are broadcast loads;
// s_src is an L2-resident 32B gather), accumulates per-head numerators
// (lane = feature) and per-head exp-sums in registers, then normalizes,
// head-means, and writes the FINAL output. No atomics, no extra buffers.
// No max-shift: attn is statistically bounded (|a| < ~15 << 88), exp() safe.
__global__ __launch_bounds__(256) void fused_aggregate(
    const int* __restrict__ csr, const int2* __restrict__ edges,
    const void* __restrict__ ef, const void* __restrict__ We,
    const float* __restrict__ s_src, const float* __restrict__ s_dst,
    const u16* __restrict__ ht, const int* __restrict__ flag,
    void* __restrict__ out)
{
    const bool bf = (*flag) != 0;
    int g = blockIdx.x * 16 + (threadIdx.x >> 4);
    if (g >= N_NODES) return;
    int lane = threadIdx.x & 15, hh8 = lane & 7;
    int beg = csr[g], end = csr[g + 1];
    float dval = s_dst[g * HEADS + hh8];
    float wev = ldf(We, hh8, bf);

    float num[8] = {0.f, 0.f, 0.f, 0.f, 0.f, 0.f, 0.f, 0.f};
    float ssum = 0.f;

    int i = beg;
    float svN = 0.f, efN = 0.f;
    bf16x8 vN = {0, 0, 0, 0, 0, 0, 0, 0};
    if (i < end) {
        int2 e0 = edges[i];
        svN = s_src[e0.x * HEADS + hh8];
        efN = ldf(ef, e0.y, bf);
        vN = *(const bf16x8*)(ht + (size_t)e0.x * IN_F + lane * 8);
    }
    for (; i < end; ++i) {
        float sv = svN, efv = efN;
        bf16x8 vC = vN;
        if (i + 1 < end) {                  // prefetch next edge
            int2 e1 = edges[i + 1];
            svN = s_src[e1.x * HEADS + hh8];
            efN = ldf(ef, e1.y, bf);
            vN = *(const bf16x8*)(ht + (size_t)e1.x * IN_F + lane * 8);
        }
        float a = sv + dval + efv * wev;
        a = (a > 0.f) ? a : 0.2f * a;       // leaky_relu 0.2
        float ex = __expf(a);
        ssum += ex;                          // head hh8 (halves duplicate)
        #pragma unroll
        for (int hh = 0; hh < 8; ++hh) {
            float ah = __shfl(ex, hh, 16);
            num[hh] = fmaf(ah, bf2f((u16)vC[hh]), num[hh]);
        }
    }

    float o = 0.f;
    #pragma unroll
    for (int hh = 0; hh < 8; ++hh) {
        float sh = __shfl(ssum, hh, 16);
        o += num[hh] / fmaxf(sh, 1e-12f);
    }
    o *= 0.125f;                             // head mean
    if (bf) ((u16*)out)[(size_t)g * OUT_F + lane] = f2bf(o);
    else    ((float*)out)[(size_t)g * OUT_F + lane] = o;
}

// ---------------------------------------------------------------- launch
extern "C" void kernel_launch(void* const* d_in, const int* in_sizes, int n_in,
                              void* d_out, int out_size, void* d_ws, size_t ws_size,
                              hipStream_t stream) {
    const void* h     = d_in[0];
    const int*  ei    = (const int*)d_in[1];
    const void* efeat = d_in[2];
    const void* Wn    = d_in[3];
    const void* We    = d_in[4];
    const void* a_src = d_in[5];
    const void* a_dst = d_in[6];

    char* ws = (char*)d_ws;
    int*   flag    = (int*)ws;   ws += 256;
    u16*   ht      = (u16*)ws;   ws += (size_t)N_NODES * IN_F * 2;     // 12.8 MB
    float* s_src   = (float*)ws; ws += (size_t)N_NODES * HEADS * 4;    // 1.6 MB
    float* s_dst   = (float*)ws; ws += (size_t)N_NODES * HEADS * 4;    // 1.6 MB
    int*   deg     = (int*)ws;   ws += (size_t)50048 * 4;              // padded
    int*   csr     = (int*)ws;   ws += (size_t)50048 * 4;              // N+1 used
    int*   cursor  = (int*)ws;   ws += (size_t)50048 * 4;
    int2*  edges   = (int2*)ws;  ws += (size_t)N_EDGES * 8;            // 6.4 MB

    hipLaunchKernelGGL(probe_dtype, dim3(1), dim3(64), 0, stream, h, flag);
    hipMemsetAsync(deg, 0, (size_t)N_NODES * 4, stream);
    hipLaunchKernelGGL(node_proj_mfma, dim3((N_NODES + 63) / 64), dim3(256),
                       0, stream, h, Wn, a_src, a_dst, flag, ht, s_src, s_dst);
    hipLaunchKernelGGL(edge_histogram, dim3((N_EDGES + 255) / 256), dim3(256),
                       0, stream, ei, deg);
    hipLaunchKernelGGL(scan_deg, dim3(1), dim3(1024), 0, stream, deg, csr, cursor);
    hipLaunchKernelGGL(scatter_edges, dim3((N_EDGES + 255) / 256), dim3(256),
                       0, stream, ei, cursor, edges);
    hipLaunchKernelGGL(fused_aggregate, dim3((N_NODES + 15) / 16), dim3(256),
                       0, stream, csr, edges, efeat, We, s_src, s_dst,
                       ht, flag, d_out);
}

// Round 5
// 236.453 us; speedup vs baseline: 1.2210x; 1.1827x over previous
//
#include <hip/hip_runtime.h>

#define N_NODES 50000
#define N_EDGES 800000
#define IN_F    128
#define HEADS   8
#define OUT_F   16
#define PROJ_THREADS 200192   // 782 blocks * 256

typedef unsigned short u16;
typedef __attribute__((ext_vector_type(8))) short bf16x8;   // 4 VGPRs
typedef __attribute__((ext_vector_type(4))) float f32x4;

__device__ __forceinline__ float bf2f(u16 u) {
    return __uint_as_float(((unsigned)u) << 16);
}
__device__ __forceinline__ u16 f2bf(float f) {
    unsigned u = __float_as_uint(f);
    unsigned r = 0x7fffu + ((u >> 16) & 1u);
    return (u16)((u + r) >> 16);
}
// dtype-adaptive float load: bf=true -> buffer is bf16, else fp32
__device__ __forceinline__ float ldf(const void* p, int i, bool bf) {
    return bf ? bf2f(((const u16*)p)[i]) : ((const float*)p)[i];
}

// ------------------------------------------------------------- dtype probe
__global__ void probe_dtype(const void* __restrict__ h, int* __restrict__ flag) {
    if (threadIdx.x == 0 && blockIdx.x == 0) {
        const u16* u = (const u16*)h;
        int cnt = 0;
        for (int i = 0; i < 128; ++i) {
            int e = (u[i] >> 7) & 0xFF;
            if (e >= 90 && e <= 141) cnt++;
        }
        *flag = (cnt >= 110) ? 1 : 0;
    }
}

// ------------------------------------- node projection (MFMA) + histogram
// ht2[n, f*8 + h] = head-interleaved projection (f=feat 0..15, h=head 0..7):
// the fused pass reads one bf16x8 (16B) per lane = 8 head-values of one
// feature; 16 lanes cover the whole 256B row coalesced.
// Histogram folded in: rank[e] = atomicAdd(deg[dst],1) -- the atomic RETURN
// is each edge's CSR slot, so the scatter pass needs no atomics at all.
// The 800k RMWs overlap with the MFMA/LDS work here.
#define WT_STRIDE 136   // bf16 units; 272 B per row: 16B-aligned, banks spread
__global__ __launch_bounds__(256) void node_proj_mfma(
    const void* __restrict__ h, const void* __restrict__ Wn,
    const void* __restrict__ a_srcp, const void* __restrict__ a_dstp,
    const int* __restrict__ flag, const int* __restrict__ ei,
    u16* __restrict__ ht, float* __restrict__ s_src, float* __restrict__ s_dst,
    int* __restrict__ deg, int* __restrict__ rank)
{
    const bool bf = (*flag) != 0;
    __shared__ u16 Wsh[IN_F * WT_STRIDE];   // 34.8 KB, Wt[c][k]
    const int tid = threadIdx.x;

    // folded histogram: 4 strided edges per thread (coalesced per iteration)
    const int tglob = blockIdx.x * 256 + tid;
    #pragma unroll
    for (int r = 0; r < 4; ++r) {
        int e = tglob + r * PROJ_THREADS;
        if (e < N_EDGES) {
            int dste = ei[N_EDGES + e];
            rank[e] = atomicAdd(&deg[dste], 1);
        }
    }

    // stage W transposed (coalesced read, scattered LDS write)
    for (int i = tid; i < IN_F * IN_F; i += 256) {
        int k = i >> 7, c = i & 127;
        u16 v = bf ? ((const u16*)Wn)[i] : f2bf(((const float*)Wn)[i]);
        Wsh[c * WT_STRIDE + k] = v;
    }
    __syncthreads();

    const int wave = tid >> 6, lane = tid & 63;
    const int m = lane & 15, q = lane >> 4;
    const int row_t = blockIdx.x * 64 + wave * 16;   // this wave's 16-row tile

    // A fragments for K=128 (4 chunks of 32)
    bf16x8 afr[4];
    int arow = row_t + m;
    if (arow >= N_NODES) arow = N_NODES - 1;         // clamp; writes guarded
    if (bf) {
        const u16* hp = (const u16*)h + (size_t)arow * IN_F;
        #pragma unroll
        for (int kt = 0; kt < 4; ++kt)
            afr[kt] = *(const bf16x8*)(hp + kt * 32 + q * 8);
    } else {
        const float* hp = (const float*)h + (size_t)arow * IN_F;
        #pragma unroll
        for (int kt = 0; kt < 4; ++kt) {
            bf16x8 t;
            #pragma unroll
            for (int j = 0; j < 8; ++j) t[j] = (short)f2bf(hp[kt * 32 + q * 8 + j]);
            afr[kt] = t;
        }
    }

    f32x4 accs[8];                                    // all 8 head tiles live
    #pragma unroll
    for (int ct = 0; ct < 8; ++ct) {                  // col tile == head
        f32x4 acc = {0.f, 0.f, 0.f, 0.f};
        #pragma unroll
        for (int kt = 0; kt < 4; ++kt) {
            bf16x8 bfr = *(const bf16x8*)(Wsh + (ct * 16 + m) * WT_STRIDE + kt * 32 + q * 8);
            acc = __builtin_amdgcn_mfma_f32_16x16x32_bf16(afr[kt], bfr, acc, 0, 0, 0);
        }
        accs[ct] = acc;
        const float asv = ldf(a_srcp, ct * 16 + m, bf);
        const float adv = ldf(a_dstp, ct * 16 + m, bf);
        float v1[4], v2[4];
        #pragma unroll
        for (int r = 0; r < 4; ++r) {
            v1[r] = acc[r] * asv;
            v2[r] = acc[r] * adv;
        }
        #pragma unroll
        for (int o = 1; o < 16; o <<= 1) {
            #pragma unroll
            for (int r = 0; r < 4; ++r) {
                v1[r] += __shfl_xor(v1[r], o, 16);
                v2[r] += __shfl_xor(v2[r], o, 16);
            }
        }
        if (m == 0) {
            #pragma unroll
            for (int r = 0; r < 4; ++r) {
                int grow = row_t + q * 4 + r;
                if (grow < N_NODES) {
                    s_src[grow * HEADS + ct] = v1[r];
                    s_dst[grow * HEADS + ct] = v2[r];
                }
            }
        }
    }

    // packed head-interleaved store: lane(m,q) owns ht2[row][m*8 + 0..7]
    #pragma unroll
    for (int r = 0; r < 4; ++r) {
        int grow = row_t + q * 4 + r;
        if (grow < N_NODES) {
            bf16x8 o;
            #pragma unroll
            for (int ct = 0; ct < 8; ++ct) o[ct] = (short)f2bf(accs[ct][r]);
            *(bf16x8*)(ht + (size_t)grow * IN_F + m * 8) = o;
        }
    }
}

// -------------------------------------------------------- exclusive scan
// Single block, two-pass: thread t sums deg[t*52 .. t*52+52), one block scan
// of the 1024 thread-sums, then each thread writes its exclusive prefixes.
// Only 2 barriers (vs 39 in the chunked version); 400 KB of L2-hot traffic.
__global__ __launch_bounds__(1024) void scan_deg(const int* __restrict__ deg,
                                                 int* __restrict__ csr) {
    __shared__ int wsums[16];
    const int tid = threadIdx.x, lane = tid & 63, wid = tid >> 6;
    const int base = tid * 52;

    // pass 1: thread-local sum
    int s = 0;
    for (int c = 0; c < 13; ++c) {
        int idx = base + c * 4;
        if (idx + 3 < N_NODES) {
            int4 q = *(const int4*)(deg + idx);
            s += q.x + q.y + q.z + q.w;
        } else {
            for (int j = 0; j < 4; ++j)
                if (idx + j < N_NODES) s += deg[idx + j];
        }
    }

    // block scan of thread sums
    int x = s;
    #pragma unroll
    for (int o = 1; o < 64; o <<= 1) {
        int y = __shfl_up(x, o, 64);
        if (lane >= o) x += y;
    }
    if (lane == 63) wsums[wid] = x;
    __syncthreads();
    if (wid == 0) {
        int v = (lane < 16) ? wsums[lane] : 0;
        #pragma unroll
        for (int o = 1; o < 16; o <<= 1) {
            int y = __shfl_up(v, o, 16);
            if ((lane & 15) >= o) v += y;
        }
        if (lane < 16) wsums[lane] = v;
    }
    __syncthreads();
    int run = ((wid > 0) ? wsums[wid - 1] : 0) + (x - s);   // exclusive offset

    // pass 2: write exclusive prefixes (deg re-read from L2)
    for (int c = 0; c < 13; ++c) {
        int idx = base + c * 4;
        if (idx + 3 < N_NODES) {
            int4 q = *(const int4*)(deg + idx);
            int4 o4 = {run, run + q.x, run + q.x + q.y, run + q.x + q.y + q.z};
            *(int4*)(csr + idx) = o4;
            run += q.x + q.y + q.z + q.w;
        } else {
            for (int j = 0; j < 4; ++j)
                if (idx + j < N_NODES) { csr[idx + j] = run; run += deg[idx + j]; }
        }
    }
    if (tid == 1023) csr[N_NODES] = run;   // grand total
}

// ------------------------------------------------------------- scatter
// NO atomics: slot = csr[dst] + rank[e] (rank captured by the histogram's
// atomic return). Payload = (src, efv bits) so the consumer never touches ef.
__global__ __launch_bounds__(256) void scatter_edges(
    const int* __restrict__ ei, const void* __restrict__ ef,
    const int* __restrict__ flag, const int* __restrict__ rank,
    const int* __restrict__ csr, int2* __restrict__ edges)
{
    const bool bf = (*flag) != 0;
    int e = blockIdx.x * 256 + threadIdx.x;
    if (e >= N_EDGES) return;
    int src = ei[e];
    int dst = ei[N_EDGES + e];
    int pos = csr[dst] + rank[e];
    float efv = ldf(ef, e, bf);
    edges[pos] = make_int2(src, __float_as_int(efv));
}

// --------------------------------------------------- fused aggregation
// One 16-lane group per dst node walks its CSR bucket: computes attn+exp
// inline (s_dst/We lane-local; edges[i] broadcast; s_src an L2/LLC-resident
// 32B gather), accumulates per-head numerators (lane = feature) and per-head
// exp-sums in registers, then normalizes, head-means, writes FINAL output.
// No atomics. ht gather hand-pipelined 1 deep.
// No max-shift: attn is statistically bounded (|a| < ~15 << 88), exp() safe.
__global__ __launch_bounds__(256) void fused_aggregate(
    const int* __restrict__ csr, const int2* __restrict__ edges,
    const void* __restrict__ We,
    const float* __restrict__ s_src, const float* __restrict__ s_dst,
    const u16* __restrict__ ht, const int* __restrict__ flag,
    void* __restrict__ out)
{
    const bool bf = (*flag) != 0;
    int g = blockIdx.x * 16 + (threadIdx.x >> 4);
    if (g >= N_NODES) return;
    int lane = threadIdx.x & 15, hh8 = lane & 7;
    int beg = csr[g], end = csr[g + 1];
    float dval = s_dst[g * HEADS + hh8];
    float wev = ldf(We, hh8, bf);

    float num[8] = {0.f, 0.f, 0.f, 0.f, 0.f, 0.f, 0.f, 0.f};
    float ssum = 0.f;

    int i = beg;
    float svN = 0.f, efN = 0.f;
    bf16x8 vN = {0, 0, 0, 0, 0, 0, 0, 0};
    if (i < end) {
        int2 e0 = edges[i];
        svN = s_src[e0.x * HEADS + hh8];
        efN = __int_as_float(e0.y);
        vN = *(const bf16x8*)(ht + (size_t)e0.x * IN_F + lane * 8);
    }
    for (; i < end; ++i) {
        float sv = svN, efv = efN;
        bf16x8 vC = vN;
        if (i + 1 < end) {                  // prefetch next edge
            int2 e1 = edges[i + 1];
            svN = s_src[e1.x * HEADS + hh8];
            efN = __int_as_float(e1.y);
            vN = *(const bf16x8*)(ht + (size_t)e1.x * IN_F + lane * 8);
        }
        float a = sv + dval + efv * wev;
        a = (a > 0.f) ? a : 0.2f * a;       // leaky_relu 0.2
        float ex = __expf(a);
        ssum += ex;                          // head hh8 (halves duplicate)
        #pragma unroll
        for (int hh = 0; hh < 8; ++hh) {
            float ah = __shfl(ex, hh, 16);
            num[hh] = fmaf(ah, bf2f((u16)vC[hh]), num[hh]);
        }
    }

    float o = 0.f;
    #pragma unroll
    for (int hh = 0; hh < 8; ++hh) {
        float sh = __shfl(ssum, hh, 16);
        o += num[hh] / fmaxf(sh, 1e-12f);
    }
    o *= 0.125f;                             // head mean
    if (bf) ((u16*)out)[(size_t)g * OUT_F + lane] = f2bf(o);
    else    ((float*)out)[(size_t)g * OUT_F + lane] = o;
}

// ---------------------------------------------------------------- launch
extern "C" void kernel_launch(void* const* d_in, const int* in_sizes, int n_in,
                              void* d_out, int out_size, void* d_ws, size_t ws_size,
                              hipStream_t stream) {
    const void* h     = d_in[0];
    const int*  ei    = (const int*)d_in[1];
    const void* efeat = d_in[2];
    const void* Wn    = d_in[3];
    const void* We    = d_in[4];
    const void* a_src = d_in[5];
    const void* a_dst = d_in[6];

    char* ws = (char*)d_ws;
    int*   flag    = (int*)ws;   ws += 256;
    u16*   ht      = (u16*)ws;   ws += (size_t)N_NODES * IN_F * 2;     // 12.8 MB
    float* s_src   = (float*)ws; ws += (size_t)N_NODES * HEADS * 4;    // 1.6 MB
    float* s_dst   = (float*)ws; ws += (size_t)N_NODES * HEADS * 4;    // 1.6 MB
    int*   deg     = (int*)ws;   ws += (size_t)50048 * 4;              // padded
    int*   csr     = (int*)ws;   ws += (size_t)50048 * 4;              // N+1 used
    int*   rank    = (int*)ws;   ws += (size_t)N_EDGES * 4;            // 3.2 MB
    int2*  edges   = (int2*)ws;  ws += (size_t)N_EDGES * 8;            // 6.4 MB

    hipLaunchKernelGGL(probe_dtype, dim3(1), dim3(64), 0, stream, h, flag);
    hipMemsetAsync(deg, 0, (size_t)N_NODES * 4, stream);
    hipLaunchKernelGGL(node_proj_mfma, dim3((N_NODES + 63) / 64), dim3(256),
                       0, stream, h, Wn, a_src, a_dst, flag, ei,
                       ht, s_src, s_dst, deg, rank);
    hipLaunchKernelGGL(scan_deg, dim3(1), dim3(1024), 0, stream, deg, csr);
    hipLaunchKernelGGL(scatter_edges, dim3((N_EDGES + 255) / 256), dim3(256),
                       0, stream, ei, efeat, flag, rank, csr, edges);
    hipLaunchKernelGGL(fused_aggregate, dim3((N_NODES + 15) / 16), dim3(256),
                       0, stream, csr, edges, We, s_src, s_dst, ht, flag, d_out);
}